// Round 1
// baseline (1120.369 us; speedup 1.0000x reference)
//
#include <hip/hip_runtime.h>

#define N_NODES 100000
#define N_EDGES 1600000
#define N_GRAPHS 64
#define DIM 128

// ---------------- CSR build ----------------

__global__ __launch_bounds__(256) void k_zero_int(int* __restrict__ p, int n) {
  int i = blockIdx.x * 256 + threadIdx.x;
  if (i < n) p[i] = 0;
}

__global__ __launch_bounds__(256) void k_hist(const int* __restrict__ ei, int* __restrict__ deg) {
  int e = blockIdx.x * 256 + threadIdx.x;
  if (e < N_EDGES) atomicAdd(&deg[ei[N_EDGES + e]], 1);
}

// exclusive scan within 256-blocks, emit block sums
__global__ __launch_bounds__(256) void k_scan1(const int* __restrict__ deg, int* __restrict__ part,
                                               int* __restrict__ bsum) {
  __shared__ int tmp[256];
  int i = blockIdx.x * 256 + threadIdx.x;
  int v = (i < N_NODES) ? deg[i] : 0;
  tmp[threadIdx.x] = v;
  __syncthreads();
  for (int o = 1; o < 256; o <<= 1) {
    int t = (threadIdx.x >= o) ? tmp[threadIdx.x - o] : 0;
    __syncthreads();
    tmp[threadIdx.x] += t;
    __syncthreads();
  }
  if (i < N_NODES) part[i] = tmp[threadIdx.x] - v;  // exclusive
  if (threadIdx.x == 255) bsum[blockIdx.x] = tmp[255];
}

__global__ __launch_bounds__(512) void k_scan2(const int* __restrict__ bsum, int* __restrict__ boff, int nb) {
  __shared__ int tmp[512];
  int v = ((int)threadIdx.x < nb) ? bsum[threadIdx.x] : 0;
  tmp[threadIdx.x] = v;
  __syncthreads();
  for (int o = 1; o < 512; o <<= 1) {
    int t = (threadIdx.x >= o) ? tmp[threadIdx.x - o] : 0;
    __syncthreads();
    tmp[threadIdx.x] += t;
    __syncthreads();
  }
  if ((int)threadIdx.x < nb) boff[threadIdx.x] = tmp[threadIdx.x] - v;  // exclusive
}

// part aliased with rowptr is safe (element-wise read->write)
__global__ __launch_bounds__(256) void k_scan3(const int* __restrict__ part, const int* __restrict__ boff,
                                               int* __restrict__ rowptr, int* __restrict__ cursor) {
  int i = blockIdx.x * 256 + threadIdx.x;
  if (i < N_NODES) {
    int r = part[i] + boff[i >> 8];
    rowptr[i] = r;
    cursor[i] = r;
  } else if (i == N_NODES) {
    rowptr[N_NODES] = N_EDGES;
  }
}

__global__ __launch_bounds__(256) void k_fill(const int* __restrict__ ei, int* __restrict__ cursor,
                                              int* __restrict__ csr) {
  int e = blockIdx.x * 256 + threadIdx.x;
  if (e < N_EDGES) {
    int d = ei[N_EDGES + e];
    int p = atomicAdd(&cursor[d], 1);
    csr[p] = ei[e];
  }
}

// ---------------- Layer 1 (IN_CH=4) ----------------

__global__ __launch_bounds__(256) void k_l1_agg(const float* __restrict__ x, const int* __restrict__ rowptr,
                                                const int* __restrict__ csr, float* __restrict__ agg4) {
  int t = blockIdx.x * 256 + threadIdx.x;
  if (t >= N_NODES * 4) return;
  int node = t >> 2, c = t & 3;
  int s = rowptr[node], e = rowptr[node + 1];
  float a = 0.f;
  for (int p = s; p < e; ++p) a += x[(size_t)csr[p] * 4 + c];
  agg4[t] = a;
}

__global__ __launch_bounds__(256) void k_l1_comb(const float* __restrict__ x, const float* __restrict__ agg4,
                                                 const float* __restrict__ w_rel, const float* __restrict__ b_rel,
                                                 const float* __restrict__ w_root, float* __restrict__ out) {
  int t = blockIdx.x * 256 + threadIdx.x;
  int node = t >> 7, c = t & 127;
  if (node >= N_NODES) return;
  float acc = b_rel[c];
#pragma unroll
  for (int k = 0; k < 4; ++k) acc += agg4[node * 4 + k] * w_rel[k * 128 + c];
#pragma unroll
  for (int k = 0; k < 4; ++k) acc += x[node * 4 + k] * w_root[k * 128 + c];
  out[(size_t)node * 128 + c] = fmaxf(acc, 0.f);
}

// ---------------- Layers 2-4: GEMM (hr = h@w_rel, hroot = h@w_root) ----------------
// BM=32, BN=128 (blockIdx.y picks w_rel/w_root), K=128 fully staged.
__global__ __launch_bounds__(256) void k_gemm(const float* __restrict__ h,
                                              const float* __restrict__ w_rel, const float* __restrict__ w_root,
                                              float* __restrict__ hr, float* __restrict__ hroot) {
  __shared__ float As[32][128];
  __shared__ float Bs[128][128];
  const float* w = (blockIdx.y == 0) ? w_rel : w_root;
  float* out = (blockIdx.y == 0) ? hr : hroot;
  int n0 = blockIdx.x * 32;
  int tid = threadIdx.x;

  for (int i = tid; i < 1024; i += 256) {  // 32 rows x 32 float4
    int m = i >> 5, kq = i & 31;
    *(float4*)&As[m][kq * 4] = *(const float4*)&h[((size_t)(n0 + m)) * 128 + kq * 4];
  }
  for (int i = tid; i < 4096; i += 256) {  // 128 rows x 32 float4
    int k = i >> 5, cq = i & 31;
    *(float4*)&Bs[k][cq * 4] = *(const float4*)&w[(size_t)k * 128 + cq * 4];
  }
  __syncthreads();

  int ct = tid & 31, rt = tid >> 5;
  int c0 = ct * 4, m0 = rt * 4;
  float acc[4][4] = {};
  for (int k = 0; k < 128; k += 4) {
    float4 a[4], b[4];
#pragma unroll
    for (int m = 0; m < 4; ++m) a[m] = *(float4*)&As[m0 + m][k];
#pragma unroll
    for (int kk = 0; kk < 4; ++kk) b[kk] = *(float4*)&Bs[k + kk][c0];
#pragma unroll
    for (int m = 0; m < 4; ++m) {
      float av;
#pragma unroll
      for (int kk = 0; kk < 4; ++kk) {
        av = ((const float*)&a[m])[kk];
        acc[m][0] += av * b[kk].x;
        acc[m][1] += av * b[kk].y;
        acc[m][2] += av * b[kk].z;
        acc[m][3] += av * b[kk].w;
      }
    }
  }
#pragma unroll
  for (int m = 0; m < 4; ++m) {
    float4 o = {acc[m][0], acc[m][1], acc[m][2], acc[m][3]};
    *(float4*)&out[((size_t)(n0 + m0 + m)) * 128 + c0] = o;
  }
}

// ---------------- Layers 2-4: aggregation + bias + root + ReLU ----------------
// One wave per dst node; lane covers 2 columns (float2 => 512B/row coalesced).
__global__ __launch_bounds__(256) void k_agg(const float* __restrict__ hr, const float* __restrict__ hroot,
                                             const float* __restrict__ bias, const int* __restrict__ rowptr,
                                             const int* __restrict__ csr, float* __restrict__ out) {
  int wid = (blockIdx.x * 256 + threadIdx.x) >> 6;
  int lane = threadIdx.x & 63;
  if (wid >= N_NODES) return;
  int s = rowptr[wid], e = rowptr[wid + 1];
  float2 acc = make_float2(0.f, 0.f);
  int p = s;
  for (; p + 4 <= e; p += 4) {
    int s0 = csr[p], s1 = csr[p + 1], s2 = csr[p + 2], s3 = csr[p + 3];
    float2 v0 = *(const float2*)&hr[(size_t)s0 * 128 + lane * 2];
    float2 v1 = *(const float2*)&hr[(size_t)s1 * 128 + lane * 2];
    float2 v2 = *(const float2*)&hr[(size_t)s2 * 128 + lane * 2];
    float2 v3 = *(const float2*)&hr[(size_t)s3 * 128 + lane * 2];
    acc.x += v0.x + v1.x + v2.x + v3.x;
    acc.y += v0.y + v1.y + v2.y + v3.y;
  }
  for (; p < e; ++p) {
    int s0 = csr[p];
    float2 v = *(const float2*)&hr[(size_t)s0 * 128 + lane * 2];
    acc.x += v.x;
    acc.y += v.y;
  }
  float2 rt = *(const float2*)&hroot[(size_t)wid * 128 + lane * 2];
  float2 bb = *(const float2*)&bias[lane * 2];
  float2 o;
  o.x = fmaxf(acc.x + rt.x + bb.x, 0.f);
  o.y = fmaxf(acc.y + rt.y + bb.y, 0.f);
  *(float2*)&out[(size_t)wid * 128 + lane * 2] = o;
}

// ---------------- Pooling ----------------

__device__ __forceinline__ int lower_bound_batch(const int* __restrict__ batch, int key) {
  int lo = 0, hi = N_NODES;
  while (lo < hi) {
    int mid = (lo + hi) >> 1;
    if (batch[mid] < key) lo = mid + 1;
    else hi = mid;
  }
  return lo;
}

// 256 blocks: 4 per graph, 2 halves in-block => 8 interleaved node streams
__global__ __launch_bounds__(256) void k_pool1(const float* __restrict__ h, const int* __restrict__ batch,
                                               float* __restrict__ psum, float* __restrict__ pmax) {
  int b = blockIdx.x;
  int g = b >> 2, q = b & 3;
  int start = lower_bound_batch(batch, g);
  int end = lower_bound_batch(batch, g + 1);
  int c = threadIdx.x & 127;
  int half = threadIdx.x >> 7;
  float sum = 0.f, mx = -3.0e38f;
  for (int n = start + q * 2 + half; n < end; n += 8) {
    float v = h[(size_t)n * 128 + c];
    sum += v;
    mx = fmaxf(mx, v);
  }
  __shared__ float ss[128], sm[128];
  if (half == 0) { ss[c] = sum; sm[c] = mx; }
  __syncthreads();
  if (half == 1) { ss[c] += sum; sm[c] = fmaxf(sm[c], mx); }
  __syncthreads();
  if (half == 0) {
    psum[(size_t)b * 128 + c] = ss[c];
    pmax[(size_t)b * 128 + c] = sm[c];
  }
}

__global__ __launch_bounds__(128) void k_pool2(const float* __restrict__ psum, const float* __restrict__ pmax,
                                               const int* __restrict__ batch, float* __restrict__ pooled) {
  int g = blockIdx.x;
  int c = threadIdx.x;
  int start = lower_bound_batch(batch, g), end = lower_bound_batch(batch, g + 1);
  int count = end - start;
  float s = 0.f, m = -3.0e38f;
#pragma unroll
  for (int q = 0; q < 4; ++q) {
    s += psum[(size_t)(g * 4 + q) * 128 + c];
    m = fmaxf(m, pmax[(size_t)(g * 4 + q) * 128 + c]);
  }
  pooled[(size_t)g * 256 + c] = (count > 0) ? m : 0.f;            // x_max first
  pooled[(size_t)g * 256 + 128 + c] = s / fmaxf((float)count, 1.f);  // x_mean second
}

// ---------------- Final FC (fused metadata branch) ----------------

__global__ __launch_bounds__(128) void k_fc(const float* __restrict__ pooled, const float* __restrict__ metadata,
                                            const float* __restrict__ convm_w, const float* __restrict__ convm_b,
                                            const float* __restrict__ fc_w, const float* __restrict__ fc_b,
                                            const float* __restrict__ fc2_w, const float* __restrict__ fc2_b,
                                            float* __restrict__ out) {
  int g = blockIdx.x;
  int tid = threadIdx.x;
  __shared__ float xc[260];
  xc[tid] = pooled[(size_t)g * 256 + tid];
  xc[128 + tid] = pooled[(size_t)g * 256 + 128 + tid];
  if (tid < 4) xc[256 + tid] = fmaxf(metadata[g] * convm_w[tid] + convm_b[tid], 0.f);
  __syncthreads();
  float acc = fc_b[tid];
  for (int k = 0; k < 260; ++k) acc += xc[k] * fc_w[(size_t)k * 128 + tid];
  float partial = fmaxf(acc, 0.f) * fc2_w[tid];
#pragma unroll
  for (int off = 32; off > 0; off >>= 1) partial += __shfl_down(partial, off);
  __shared__ float wred[2];
  if ((tid & 63) == 0) wred[tid >> 6] = partial;
  __syncthreads();
  if (tid == 0) out[g] = wred[0] + wred[1] + fc2_b[0];
}

// ---------------- launch ----------------

extern "C" void kernel_launch(void* const* d_in, const int* in_sizes, int n_in,
                              void* d_out, int out_size, void* d_ws, size_t ws_size,
                              hipStream_t stream) {
  const float* x = (const float*)d_in[0];
  const float* metadata = (const float*)d_in[1];
  const int* ei = (const int*)d_in[2];
  const int* batch = (const int*)d_in[3];
  const float* w_rel[4] = {(const float*)d_in[4], (const float*)d_in[7], (const float*)d_in[10], (const float*)d_in[13]};
  const float* b_rel[4] = {(const float*)d_in[5], (const float*)d_in[8], (const float*)d_in[11], (const float*)d_in[14]};
  const float* w_root[4] = {(const float*)d_in[6], (const float*)d_in[9], (const float*)d_in[12], (const float*)d_in[15]};
  const float* convm_w = (const float*)d_in[16];
  const float* convm_b = (const float*)d_in[17];
  const float* fc_w = (const float*)d_in[18];
  const float* fc_b = (const float*)d_in[19];
  const float* fc2_w = (const float*)d_in[20];
  const float* fc2_b = (const float*)d_in[21];
  float* out = (float*)d_out;

  char* ws = (char*)d_ws;
  size_t off = 0;
  auto alloc = [&](size_t bytes) {
    off = (off + 255) & ~(size_t)255;
    void* p = ws + off;
    off += bytes;
    return p;
  };
  int* deg = (int*)alloc((size_t)N_NODES * 4);
  int* rowptr = (int*)alloc((size_t)(N_NODES + 1) * 4);
  int* cursor = (int*)alloc((size_t)N_NODES * 4);
  int* bsum = (int*)alloc(512 * 4);
  int* boff = (int*)alloc(512 * 4);
  int* csr = (int*)alloc((size_t)N_EDGES * 4);
  float* agg4 = (float*)alloc((size_t)N_NODES * 4 * 4);
  float* bufA = (float*)alloc((size_t)N_NODES * 128 * 4);
  float* bufB = (float*)alloc((size_t)N_NODES * 128 * 4);
  float* bufC = (float*)alloc((size_t)N_NODES * 128 * 4);
  float* psum = (float*)alloc((size_t)256 * 128 * 4);
  float* pmax = (float*)alloc((size_t)256 * 128 * 4);
  float* pooled = (float*)alloc((size_t)64 * 256 * 4);

  const int nblk_nodes = (N_NODES + 255) / 256;         // 391
  const int nblk_edges = (N_EDGES + 255) / 256;         // 6250

  k_zero_int<<<nblk_nodes, 256, 0, stream>>>(deg, N_NODES);
  k_hist<<<nblk_edges, 256, 0, stream>>>(ei, deg);
  k_scan1<<<nblk_nodes, 256, 0, stream>>>(deg, rowptr, bsum);
  k_scan2<<<1, 512, 0, stream>>>(bsum, boff, nblk_nodes);
  k_scan3<<<(N_NODES + 1 + 255) / 256, 256, 0, stream>>>(rowptr, boff, rowptr, cursor);
  k_fill<<<nblk_edges, 256, 0, stream>>>(ei, cursor, csr);

  // Layer 1
  k_l1_agg<<<(N_NODES * 4 + 255) / 256, 256, 0, stream>>>(x, rowptr, csr, agg4);
  k_l1_comb<<<(N_NODES * 128 + 255) / 256, 256, 0, stream>>>(x, agg4, w_rel[0], b_rel[0], w_root[0], bufA);

  // Layers 2-4
  for (int l = 1; l < 4; ++l) {
    dim3 gg(3125, 2);
    k_gemm<<<gg, 256, 0, stream>>>(bufA, w_rel[l], w_root[l], bufB, bufC);
    k_agg<<<(N_NODES + 3) / 4, 256, 0, stream>>>(bufB, bufC, b_rel[l], rowptr, csr, bufA);
  }

  // Pool + FC
  k_pool1<<<256, 256, 0, stream>>>(bufA, batch, psum, pmax);
  k_pool2<<<64, 128, 0, stream>>>(psum, pmax, batch, pooled);
  k_fc<<<64, 128, 0, stream>>>(pooled, metadata, convm_w, convm_b, fc_w, fc_b, fc2_w, fc2_b, out);
}